// Round 1
// baseline (2515.366 us; speedup 1.0000x reference)
//
#include <hip/hip_runtime.h>
#include <math.h>

// Problem constants
#define Bsz 16
#define Kpt 4096
#define Cft 256
#define Pnp 1024
#define Smp 16
#define Hch 128
#define OUTCH 22
#define M0 (Bsz * Pnp * Smp)   // 262144
#define M1 (Bsz * Pnp)         // 16384

// Workspace layout (in floats)
#define OFF_FT      ((size_t)0)                    // 16777216  ft: (B,K,C)
#define OFF_YA      ((size_t)16777216)             // 33554432  activations (M0 x 128)
#define OFF_AGG     ((size_t)50331648)             // 2097152   agg (M1 x 128)
#define OFF_YF      ((size_t)52428800)             // 2097152   FC activations (M1 x 128)
#define OFF_W0T     ((size_t)54525952)             // 32768     w0 feat part transposed (256x128)
#define OFF_W1T     ((size_t)54558720)             // 16384
#define OFF_W2T     ((size_t)54575104)             // 16384
#define OFF_WF1T    ((size_t)54591488)             // 16384
#define OFF_WF2T    ((size_t)54607872)             // 16384
#define OFF_STATS   ((size_t)54624256)             // 5*256
#define OFF_GIDX    ((size_t)54625536)             // 262144 (int)
#define OFF_NEWXYZ  ((size_t)54887680)             // 49152

// ---------------------------------------------------------------- transpose features (B,C,K)->(B,K,C)
__global__ __launch_bounds__(256) void transpose_feat(const float* __restrict__ f, float* __restrict__ ft) {
    __shared__ float tile[32][33];
    int b = blockIdx.z;
    int k0 = blockIdx.x * 32, c0 = blockIdx.y * 32;
    int tx = threadIdx.x, ty = threadIdx.y; // 32 x 8
#pragma unroll
    for (int j = 0; j < 4; ++j) {
        int c = c0 + ty + j * 8;
        tile[ty + j * 8][tx] = f[((size_t)b * Cft + c) * Kpt + k0 + tx];
    }
    __syncthreads();
#pragma unroll
    for (int j = 0; j < 4; ++j) {
        int k = k0 + ty + j * 8;
        ft[((size_t)b * Kpt + k) * Cft + c0 + tx] = tile[tx][ty + j * 8];
    }
}

// ---------------------------------------------------------------- small weight transpose dst[c*O+o]=src[o*stride+off+c]
__global__ __launch_bounds__(256) void transpose_w(const float* __restrict__ src, float* __restrict__ dst,
                                                   int O, int Cs, int stride, int off) {
    int idx = blockIdx.x * 256 + threadIdx.x;
    if (idx < O * Cs) {
        int o = idx % O, c = idx / O;
        dst[idx] = src[(size_t)o * stride + off + c];
    }
}

// ---------------------------------------------------------------- FPS: one block per batch
__global__ __launch_bounds__(1024) void fps_kernel(const float* __restrict__ xyz, float* __restrict__ new_xyz) {
    __shared__ float xyz_s[Kpt * 3];
    __shared__ float red_v[16];
    __shared__ int red_i[16];
    __shared__ int last_s;
    int b = blockIdx.x, tid = threadIdx.x;
    for (int e = tid; e < Kpt * 3; e += 1024) xyz_s[e] = xyz[(size_t)b * Kpt * 3 + e];
    if (tid == 0) {
        last_s = 0;
        new_xyz[(size_t)b * Pnp * 3 + 0] = xyz[(size_t)b * Kpt * 3 + 0];
        new_xyz[(size_t)b * Pnp * 3 + 1] = xyz[(size_t)b * Kpt * 3 + 1];
        new_xyz[(size_t)b * Pnp * 3 + 2] = xyz[(size_t)b * Kpt * 3 + 2];
    }
    float mind[4] = {1e10f, 1e10f, 1e10f, 1e10f};
    __syncthreads();
    int last = 0;
    for (int it = 1; it < Pnp; ++it) {
        float lx = xyz_s[last * 3 + 0], ly = xyz_s[last * 3 + 1], lz = xyz_s[last * 3 + 2];
        float bestv = -1.0f;
        int besti = 0;
#pragma unroll
        for (int j = 0; j < 4; ++j) {
            int k = tid + j * 1024;
            float dx = __fsub_rn(xyz_s[k * 3 + 0], lx);
            float dy = __fsub_rn(xyz_s[k * 3 + 1], ly);
            float dz = __fsub_rn(xyz_s[k * 3 + 2], lz);
            float d = __fadd_rn(__fadd_rn(__fmul_rn(dx, dx), __fmul_rn(dy, dy)), __fmul_rn(dz, dz));
            mind[j] = fminf(mind[j], d);
            if (mind[j] > bestv) { bestv = mind[j]; besti = k; }
        }
#pragma unroll
        for (int off = 32; off >= 1; off >>= 1) {
            float ov = __shfl_down(bestv, off, 64);
            int oi = __shfl_down(besti, off, 64);
            if (ov > bestv || (ov == bestv && oi < besti)) { bestv = ov; besti = oi; }
        }
        if ((tid & 63) == 0) { red_v[tid >> 6] = bestv; red_i[tid >> 6] = besti; }
        __syncthreads();
        if (tid < 16) {
            bestv = red_v[tid]; besti = red_i[tid];
#pragma unroll
            for (int off = 8; off >= 1; off >>= 1) {
                float ov = __shfl_down(bestv, off, 16);
                int oi = __shfl_down(besti, off, 16);
                if (ov > bestv || (ov == bestv && oi < besti)) { bestv = ov; besti = oi; }
            }
            if (tid == 0) {
                last_s = besti;
                size_t bp = (size_t)b * Pnp + it;
                new_xyz[bp * 3 + 0] = xyz_s[besti * 3 + 0];
                new_xyz[bp * 3 + 1] = xyz_s[besti * 3 + 1];
                new_xyz[bp * 3 + 2] = xyz_s[besti * 3 + 2];
            }
        }
        __syncthreads();
        last = last_s;
    }
}

// ---------------------------------------------------------------- ball query
__global__ __launch_bounds__(256) void ballq_kernel(const float* __restrict__ xyz, const float* __restrict__ new_xyz,
                                                    int* __restrict__ gidx) {
    __shared__ float xyz_s[Kpt * 3];
    __shared__ int idxbuf[64][16];
    __shared__ int have_s[64];
    int bx = blockIdx.x;
    int b = bx >> 4, chunk = bx & 15;
    int tid = threadIdx.x, w = tid >> 6, lane = tid & 63;
    for (int e = tid; e < Kpt * 3; e += 256) xyz_s[e] = xyz[(size_t)b * Kpt * 3 + e];
    __syncthreads();
    const float R2 = (float)(0.3 * 0.3);
    unsigned long long lmask = (lane == 63) ? 0x7fffffffffffffffull : ((1ull << lane) - 1ull);
    for (int t = 0; t < 16; ++t) {
        int ql = w * 16 + t;
        size_t bp = (size_t)b * Pnp + chunk * 64 + ql;
        float nx = new_xyz[bp * 3 + 0], ny = new_xyz[bp * 3 + 1], nz = new_xyz[bp * 3 + 2];
        int have = 0;
        for (int r = 0; r < 64; ++r) {
            int k = r * 64 + lane;
            float dx = __fsub_rn(nx, xyz_s[k * 3 + 0]);
            float dy = __fsub_rn(ny, xyz_s[k * 3 + 1]);
            float dz = __fsub_rn(nz, xyz_s[k * 3 + 2]);
            float d2 = __fadd_rn(__fadd_rn(__fmul_rn(dx, dx), __fmul_rn(dy, dy)), __fmul_rn(dz, dz));
            bool inb = d2 < R2;
            unsigned long long mask = __ballot(inb);
            if (mask) {
                int rank = __popcll(mask & lmask);
                if (inb && (have + rank) < 16) idxbuf[ql][have + rank] = k;
                have += __popcll(mask);
                if (have >= 16) break;
            }
        }
        if (lane == 0) have_s[ql] = (have > 16) ? 16 : have;
    }
    __syncthreads();
    for (int e = tid; e < 1024; e += 256) {
        int ql = e >> 4, slot = e & 15;
        int h = have_s[ql];
        int v = (h == 0) ? (Kpt - 1) : ((slot < h) ? idxbuf[ql][slot] : idxbuf[ql][0]);
        size_t bp = (size_t)b * Pnp + chunk * 64 + ql;
        gidx[bp * 16 + slot] = v;
    }
}

// ---------------------------------------------------------------- GEMM layer0: gathered input, y = h @ w0^T
__global__ __launch_bounds__(256) void gemm_gather(const float* __restrict__ ft, const float* __restrict__ w0t,
                                                   const float* __restrict__ xyz, const float* __restrict__ new_xyz,
                                                   const int* __restrict__ gidx, const float* __restrict__ w0,
                                                   float* __restrict__ yout) {
    __shared__ float As[32][68];
    __shared__ float Bs[32][132];
    __shared__ float gxyz_s[64][4];
    __shared__ float w03s[128][4];
    __shared__ int k_s[64];
    int tid = threadIdx.x;
    size_t rblk = (size_t)blockIdx.x * 64;
    int b = (int)(rblk >> 14); // /16384
    if (tid < 64) {
        size_t r = rblk + tid;
        int kg = gidx[r];
        k_s[tid] = kg;
        size_t bp = r >> 4;
#pragma unroll
        for (int c = 0; c < 3; ++c) {
            float gx = (xyz[((size_t)b * Kpt + kg) * 3 + c] - new_xyz[bp * 3 + c]) / 0.3f;
            gxyz_s[tid][c] = gx;
        }
    } else if (tid < 192) {
        int o = tid - 64;
#pragma unroll
        for (int c = 0; c < 3; ++c) w03s[o][c] = w0[(size_t)o * 259 + c];
    }
    __syncthreads();
    int i = tid >> 2, cq = tid & 3;
    const float* Arow = ft + ((size_t)b * Kpt + k_s[i]) * Cft;
    int kkB = tid >> 3, oq = tid & 7;
    int ty = tid >> 4, tx = tid & 15;
    float acc[4][8];
#pragma unroll
    for (int ii = 0; ii < 4; ++ii)
#pragma unroll
        for (int jj = 0; jj < 8; ++jj) acc[ii][jj] = 0.f;

    for (int kt = 0; kt < 8; ++kt) {
        int c0 = kt * 32;
        float4 a0 = *(const float4*)(Arow + c0 + cq * 4);
        float4 a1 = *(const float4*)(Arow + c0 + cq * 4 + 16);
        float4 bv[4];
#pragma unroll
        for (int q = 0; q < 4; ++q)
            bv[q] = *(const float4*)(w0t + (size_t)(c0 + kkB) * 128 + oq * 16 + q * 4);
        __syncthreads();
        As[cq * 4 + 0][i] = a0.x; As[cq * 4 + 1][i] = a0.y; As[cq * 4 + 2][i] = a0.z; As[cq * 4 + 3][i] = a0.w;
        As[cq * 4 + 16][i] = a1.x; As[cq * 4 + 17][i] = a1.y; As[cq * 4 + 18][i] = a1.z; As[cq * 4 + 19][i] = a1.w;
#pragma unroll
        for (int q = 0; q < 4; ++q)
            *(float4*)&Bs[kkB][oq * 16 + q * 4] = bv[q];
        __syncthreads();
#pragma unroll
        for (int kk = 0; kk < 32; ++kk) {
            float4 av = *(const float4*)&As[kk][ty * 4];
            float4 b0 = *(const float4*)&Bs[kk][tx * 8];
            float4 b1 = *(const float4*)&Bs[kk][tx * 8 + 4];
            float a_[4] = {av.x, av.y, av.z, av.w};
            float b_[8] = {b0.x, b0.y, b0.z, b0.w, b1.x, b1.y, b1.z, b1.w};
#pragma unroll
            for (int ii = 0; ii < 4; ++ii)
#pragma unroll
                for (int jj = 0; jj < 8; ++jj) acc[ii][jj] += a_[ii] * b_[jj];
        }
    }
    // epilogue: xyz rank-3 contribution + store
#pragma unroll
    for (int ii = 0; ii < 4; ++ii) {
        int rowl = ty * 4 + ii;
        float g0 = gxyz_s[rowl][0], g1 = gxyz_s[rowl][1], g2 = gxyz_s[rowl][2];
        float out[8];
#pragma unroll
        for (int jj = 0; jj < 8; ++jj) {
            int o = tx * 8 + jj;
            out[jj] = acc[ii][jj] + g0 * w03s[o][0] + g1 * w03s[o][1] + g2 * w03s[o][2];
        }
        size_t row = rblk + rowl;
        *(float4*)(yout + row * 128 + tx * 8) = make_float4(out[0], out[1], out[2], out[3]);
        *(float4*)(yout + row * 128 + tx * 8 + 4) = make_float4(out[4], out[5], out[6], out[7]);
    }
}

// ---------------------------------------------------------------- generic GEMM with optional fused input-BN-ReLU; may run in place
__global__ __launch_bounds__(256) void gemm_bn(const float* Ain, const float* __restrict__ wt, float* Aout,
                                               const float* __restrict__ stats, const float* __restrict__ gamma,
                                               const float* __restrict__ beta, const float* __restrict__ bias,
                                               int Kc, float invN) {
    __shared__ float As[32][68];
    __shared__ float Bs[32][132];
    __shared__ float scs[128], shs[128];
    int tid = threadIdx.x;
    bool hasT = (stats != nullptr);
    if (hasT && tid < 128) {
        float m = stats[tid] * invN;
        float v = stats[128 + tid] * invN - m * m;
        float sc = gamma[tid] / sqrtf(v + 1e-5f);
        scs[tid] = sc;
        shs[tid] = beta[tid] - m * sc;
    }
    size_t rblk = (size_t)blockIdx.x * 64;
    int i = tid >> 2, cq = tid & 3;
    const float* Arow = Ain + (rblk + i) * Kc;
    int kkB = tid >> 3, oq = tid & 7;
    int ty = tid >> 4, tx = tid & 15;
    float acc[4][8];
#pragma unroll
    for (int ii = 0; ii < 4; ++ii)
#pragma unroll
        for (int jj = 0; jj < 8; ++jj) acc[ii][jj] = 0.f;

    int nk = Kc >> 5;
    for (int kt = 0; kt < nk; ++kt) {
        int c0 = kt * 32;
        float4 a0 = *(const float4*)(Arow + c0 + cq * 4);
        float4 a1 = *(const float4*)(Arow + c0 + cq * 4 + 16);
        float4 bv[4];
#pragma unroll
        for (int q = 0; q < 4; ++q)
            bv[q] = *(const float4*)(wt + (size_t)(c0 + kkB) * 128 + oq * 16 + q * 4);
        __syncthreads();
        if (hasT) {
            int cb = c0 + cq * 4;
            a0.x = fmaxf(0.f, a0.x * scs[cb + 0] + shs[cb + 0]);
            a0.y = fmaxf(0.f, a0.y * scs[cb + 1] + shs[cb + 1]);
            a0.z = fmaxf(0.f, a0.z * scs[cb + 2] + shs[cb + 2]);
            a0.w = fmaxf(0.f, a0.w * scs[cb + 3] + shs[cb + 3]);
            a1.x = fmaxf(0.f, a1.x * scs[cb + 16] + shs[cb + 16]);
            a1.y = fmaxf(0.f, a1.y * scs[cb + 17] + shs[cb + 17]);
            a1.z = fmaxf(0.f, a1.z * scs[cb + 18] + shs[cb + 18]);
            a1.w = fmaxf(0.f, a1.w * scs[cb + 19] + shs[cb + 19]);
        }
        As[cq * 4 + 0][i] = a0.x; As[cq * 4 + 1][i] = a0.y; As[cq * 4 + 2][i] = a0.z; As[cq * 4 + 3][i] = a0.w;
        As[cq * 4 + 16][i] = a1.x; As[cq * 4 + 17][i] = a1.y; As[cq * 4 + 18][i] = a1.z; As[cq * 4 + 19][i] = a1.w;
#pragma unroll
        for (int q = 0; q < 4; ++q)
            *(float4*)&Bs[kkB][oq * 16 + q * 4] = bv[q];
        __syncthreads();
#pragma unroll
        for (int kk = 0; kk < 32; ++kk) {
            float4 av = *(const float4*)&As[kk][ty * 4];
            float4 b0 = *(const float4*)&Bs[kk][tx * 8];
            float4 b1 = *(const float4*)&Bs[kk][tx * 8 + 4];
            float a_[4] = {av.x, av.y, av.z, av.w};
            float b_[8] = {b0.x, b0.y, b0.z, b0.w, b1.x, b1.y, b1.z, b1.w};
#pragma unroll
            for (int ii = 0; ii < 4; ++ii)
#pragma unroll
                for (int jj = 0; jj < 8; ++jj) acc[ii][jj] += a_[ii] * b_[jj];
        }
    }
#pragma unroll
    for (int ii = 0; ii < 4; ++ii) {
        size_t row = rblk + ty * 4 + ii;
        float out[8];
#pragma unroll
        for (int jj = 0; jj < 8; ++jj) {
            int o = tx * 8 + jj;
            out[jj] = acc[ii][jj] + (bias ? bias[o] : 0.f);
        }
        *(float4*)(Aout + row * 128 + tx * 8) = make_float4(out[0], out[1], out[2], out[3]);
        *(float4*)(Aout + row * 128 + tx * 8 + 4) = make_float4(out[4], out[5], out[6], out[7]);
    }
}

// ---------------------------------------------------------------- per-channel sum/sumsq (stats pre-zeroed)
__global__ __launch_bounds__(256) void stats_k(const float* __restrict__ y, float* __restrict__ st) {
    __shared__ float ssum[256], ssq[256];
    int tid = threadIdx.x;
    int o = tid & 127, h = tid >> 7;
    size_t r0 = (size_t)blockIdx.x * 256;
    float sum = 0.f, sq = 0.f;
#pragma unroll 4
    for (int i = 0; i < 128; ++i) {
        float v = y[(r0 + i * 2 + h) * 128 + o];
        sum += v;
        sq += v * v;
    }
    ssum[tid] = sum; ssq[tid] = sq;
    __syncthreads();
    if (tid < 128) {
        atomicAdd(&st[o], ssum[tid] + ssum[tid + 128]);
        atomicAdd(&st[128 + o], ssq[tid] + ssq[tid + 128]);
    }
}

// ---------------------------------------------------------------- BN+ReLU+max over s
__global__ __launch_bounds__(256) void maxpool_k(const float* __restrict__ y, const float* __restrict__ st,
                                                 const float* __restrict__ gamma, const float* __restrict__ beta,
                                                 float* __restrict__ agg) {
    int tid = threadIdx.x;
    int o = tid & 127, h = tid >> 7;
    size_t bp = (size_t)blockIdx.x * 2 + h;
    const float invN = 1.f / (float)M0;
    float m = st[o] * invN;
    float v = st[128 + o] * invN - m * m;
    float sc = gamma[o] / sqrtf(v + 1e-5f);
    float sh = beta[o] - m * sc;
    float best = 0.f;
#pragma unroll
    for (int s = 0; s < 16; ++s) {
        float vv = y[(bp * 16 + s) * 128 + o];
        best = fmaxf(best, fmaxf(0.f, vv * sc + sh));
    }
    agg[bp * 128 + o] = best;
}

// ---------------------------------------------------------------- final: n2=BN-ReLU(yf), net=n2@w3^T+b3, out assembly
__global__ __launch_bounds__(256) void final_k(const float* __restrict__ yf, const float* __restrict__ st,
                                               const float* __restrict__ gamma, const float* __restrict__ beta,
                                               const float* __restrict__ w3, const float* __restrict__ b3,
                                               const float* __restrict__ new_xyz, float* __restrict__ out) {
    __shared__ float n2s[8][128];
    __shared__ float w3s[22 * 132];
    __shared__ float scf[128], shf[128];
    int tid = threadIdx.x;
    size_t r0 = (size_t)blockIdx.x * 8;
    if (tid < 128) {
        const float invN = 1.f / (float)M1;
        float m = st[tid] * invN;
        float v = st[128 + tid] * invN - m * m;
        float sc = gamma[tid] / sqrtf(v + 1e-5f);
        scf[tid] = sc;
        shf[tid] = beta[tid] - m * sc;
    }
    __syncthreads();
#pragma unroll
    for (int i = 0; i < 4; ++i) {
        int e = tid + i * 256;
        int rl = e >> 7, c = e & 127;
        float raw = yf[(r0 + rl) * 128 + c];
        n2s[rl][c] = fmaxf(0.f, raw * scf[c] + shf[c]);
    }
#pragma unroll
    for (int i = 0; i < 11; ++i) {
        int e = tid + i * 256;
        int o = e >> 7, c = e & 127;
        w3s[o * 132 + c] = w3[e];
    }
    __syncthreads();
    int rl = tid >> 5, o = tid & 31;
    if (o < OUTCH) {
        float dot = 0.f;
#pragma unroll 4
        for (int c = 0; c < 128; ++c) dot += n2s[rl][c] * w3s[o * 132 + c];
        float v = dot + b3[o];
        if (o < 3) v += new_xyz[(r0 + rl) * 3 + o];
        out[(r0 + rl) * OUTCH + o] = v;
    }
}

extern "C" void kernel_launch(void* const* d_in, const int* in_sizes, int n_in,
                              void* d_out, int out_size, void* d_ws, size_t ws_size,
                              hipStream_t stream) {
    (void)in_sizes; (void)n_in; (void)out_size; (void)ws_size;
    const float* xyz = (const float*)d_in[0];
    const float* features = (const float*)d_in[1];
    const float* w0 = (const float*)d_in[2];
    const float* g0 = (const float*)d_in[3];
    const float* be0 = (const float*)d_in[4];
    const float* w1m = (const float*)d_in[5];
    const float* g1m = (const float*)d_in[6];
    const float* be1m = (const float*)d_in[7];
    const float* w2m = (const float*)d_in[8];
    const float* g2m = (const float*)d_in[9];
    const float* be2m = (const float*)d_in[10];
    const float* wf1 = (const float*)d_in[11];
    const float* bf1 = (const float*)d_in[12];
    const float* gf1 = (const float*)d_in[13];
    const float* bef1 = (const float*)d_in[14];
    const float* wf2 = (const float*)d_in[15];
    const float* bf2 = (const float*)d_in[16];
    const float* gf2 = (const float*)d_in[17];
    const float* bef2 = (const float*)d_in[18];
    const float* w3 = (const float*)d_in[19];
    const float* b3 = (const float*)d_in[20];
    float* ws = (float*)d_ws;
    float* ft = ws + OFF_FT;
    float* yA = ws + OFF_YA;
    float* agg = ws + OFF_AGG;
    float* yF = ws + OFF_YF;
    float* st = ws + OFF_STATS;
    int* gidx = (int*)(ws + OFF_GIDX);
    float* nxyz = ws + OFF_NEWXYZ;

    hipMemsetAsync((void*)st, 0, 5 * 256 * sizeof(float), stream);

    transpose_feat<<<dim3(Kpt / 32, Cft / 32, Bsz), dim3(32, 8), 0, stream>>>(features, ft);
    transpose_w<<<128, 256, 0, stream>>>(w0, ws + OFF_W0T, 128, 256, 259, 3);
    transpose_w<<<64, 256, 0, stream>>>(w1m, ws + OFF_W1T, 128, 128, 128, 0);
    transpose_w<<<64, 256, 0, stream>>>(w2m, ws + OFF_W2T, 128, 128, 128, 0);
    transpose_w<<<64, 256, 0, stream>>>(wf1, ws + OFF_WF1T, 128, 128, 128, 0);
    transpose_w<<<64, 256, 0, stream>>>(wf2, ws + OFF_WF2T, 128, 128, 128, 0);

    fps_kernel<<<Bsz, 1024, 0, stream>>>(xyz, nxyz);
    ballq_kernel<<<256, 256, 0, stream>>>(xyz, nxyz, gidx);

    gemm_gather<<<M0 / 64, 256, 0, stream>>>(ft, ws + OFF_W0T, xyz, nxyz, gidx, w0, yA);
    stats_k<<<M0 / 256, 256, 0, stream>>>(yA, st);
    gemm_bn<<<M0 / 64, 256, 0, stream>>>(yA, ws + OFF_W1T, yA, st, g0, be0, nullptr, 128, 1.f / (float)M0);
    stats_k<<<M0 / 256, 256, 0, stream>>>(yA, st + 256);
    gemm_bn<<<M0 / 64, 256, 0, stream>>>(yA, ws + OFF_W2T, yA, st + 256, g1m, be1m, nullptr, 128, 1.f / (float)M0);
    stats_k<<<M0 / 256, 256, 0, stream>>>(yA, st + 512);
    maxpool_k<<<M1 / 2, 256, 0, stream>>>(yA, st + 512, g2m, be2m, agg);

    gemm_bn<<<M1 / 64, 256, 0, stream>>>(agg, ws + OFF_WF1T, yF, nullptr, nullptr, nullptr, bf1, 128, 0.f);
    stats_k<<<M1 / 256, 256, 0, stream>>>(yF, st + 768);
    gemm_bn<<<M1 / 64, 256, 0, stream>>>(yF, ws + OFF_WF2T, yF, st + 768, gf1, bef1, bf2, 128, 1.f / (float)M1);
    stats_k<<<M1 / 256, 256, 0, stream>>>(yF, st + 1024);
    final_k<<<M1 / 8, 256, 0, stream>>>(yF, st + 1024, gf2, bef2, w3, b3, nxyz, (float*)d_out);
}

// Round 2
// 1833.805 us; speedup vs baseline: 1.3717x; 1.3717x over previous
//
#include <hip/hip_runtime.h>
#include <math.h>

// Problem constants
#define Bsz 16
#define Kpt 4096
#define Cft 256
#define Pnp 1024
#define Smp 16
#define Hch 128
#define OUTCH 22
#define M0 (Bsz * Pnp * Smp)   // 262144
#define M1 (Bsz * Pnp)         // 16384

// Workspace layout (in floats)
#define OFF_FT      ((size_t)0)                    // 16777216  ft: (B,K,C)
#define OFF_YA      ((size_t)16777216)             // 33554432  activations (M0 x 128)
#define OFF_AGG     ((size_t)50331648)             // 2097152   agg (M1 x 128)
#define OFF_YF      ((size_t)52428800)             // 2097152   FC activations (M1 x 128)
#define OFF_W0T     ((size_t)54525952)             // 32768     w0 feat part transposed (256x128)
#define OFF_W1T     ((size_t)54558720)             // 16384
#define OFF_W2T     ((size_t)54575104)             // 16384
#define OFF_WF1T    ((size_t)54591488)             // 16384
#define OFF_WF2T    ((size_t)54607872)             // 16384
#define OFF_STATS   ((size_t)54624256)             // 5*256
#define OFF_GIDX    ((size_t)54625536)             // 262144 (int)
#define OFF_NEWXYZ  ((size_t)54887680)             // 49152

// ---------------------------------------------------------------- transpose features (B,C,K)->(B,K,C)
__global__ __launch_bounds__(256) void transpose_feat(const float* __restrict__ f, float* __restrict__ ft) {
    __shared__ float tile[32][33];
    int b = blockIdx.z;
    int k0 = blockIdx.x * 32, c0 = blockIdx.y * 32;
    int tx = threadIdx.x, ty = threadIdx.y; // 32 x 8
#pragma unroll
    for (int j = 0; j < 4; ++j) {
        int c = c0 + ty + j * 8;
        tile[ty + j * 8][tx] = f[((size_t)b * Cft + c) * Kpt + k0 + tx];
    }
    __syncthreads();
#pragma unroll
    for (int j = 0; j < 4; ++j) {
        int k = k0 + ty + j * 8;
        ft[((size_t)b * Kpt + k) * Cft + c0 + tx] = tile[tx][ty + j * 8];
    }
}

// ---------------------------------------------------------------- small weight transpose dst[c*O+o]=src[o*stride+off+c]
__global__ __launch_bounds__(256) void transpose_w(const float* __restrict__ src, float* __restrict__ dst,
                                                   int O, int Cs, int stride, int off) {
    int idx = blockIdx.x * 256 + threadIdx.x;
    if (idx < O * Cs) {
        int o = idx % O, c = idx / O;
        dst[idx] = src[(size_t)o * stride + off + c];
    }
}

// ---------------------------------------------------------------- FPS: one block per batch, 512 threads,
// points + running-min distances register-resident; packed u64 argmax key; 1 barrier/iter.
__global__ __launch_bounds__(512) void fps_kernel(const float* __restrict__ xyz, float* __restrict__ new_xyz) {
    __shared__ float4 xyz_s[Kpt];                 // padded stride-4: one ds_read_b128 for winner coords
    __shared__ unsigned long long red[2][8];      // parity-double-buffered per-wave winners
    int b = blockIdx.x, tid = threadIdx.x;
    int wid = tid >> 6, lane = tid & 63;

    for (int k = tid; k < Kpt; k += 512) {
        float x = xyz[(size_t)b * Kpt * 3 + k * 3 + 0];
        float y = xyz[(size_t)b * Kpt * 3 + k * 3 + 1];
        float z = xyz[(size_t)b * Kpt * 3 + k * 3 + 2];
        xyz_s[k] = make_float4(x, y, z, 0.f);
    }
    __syncthreads();

    float px[8], py[8], pz[8], mind[8];
#pragma unroll
    for (int j = 0; j < 8; ++j) {
        float4 p = xyz_s[tid + j * 512];
        px[j] = p.x; py[j] = p.y; pz[j] = p.z;
        mind[j] = 1e10f;
    }
    float lx = xyz_s[0].x, ly = xyz_s[0].y, lz = xyz_s[0].z;
    if (tid == 0) {
        new_xyz[(size_t)b * Pnp * 3 + 0] = lx;
        new_xyz[(size_t)b * Pnp * 3 + 1] = ly;
        new_xyz[(size_t)b * Pnp * 3 + 2] = lz;
    }

    for (int it = 1; it < Pnp; ++it) {
        // local update + argmax (exact reference arithmetic: no fma contraction)
        float bestv = -1.0f;
        int bestk = 0;
#pragma unroll
        for (int j = 0; j < 8; ++j) {
            float dx = __fsub_rn(px[j], lx);
            float dy = __fsub_rn(py[j], ly);
            float dz = __fsub_rn(pz[j], lz);
            float d = __fadd_rn(__fadd_rn(__fmul_rn(dx, dx), __fmul_rn(dy, dy)), __fmul_rn(dz, dz));
            float m = fminf(mind[j], d);
            mind[j] = m;
            if (m > bestv) { bestv = m; bestk = tid + j * 512; }  // strict > : lowest k on ties
        }
        // pack: d>=0 so float bit-order == value order; ~k gives lowest-index tie-break under max
        unsigned long long key = ((unsigned long long)__float_as_uint(bestv) << 32) | (unsigned)(~bestk);
#pragma unroll
        for (int off = 32; off >= 1; off >>= 1) {
            unsigned long long ok = __shfl_down(key, off, 64);
            if (ok > key) key = ok;
        }
        if (lane == 0) red[it & 1][wid] = key;
        __syncthreads();
        unsigned long long gkey = red[it & 1][0];
#pragma unroll
        for (int w = 1; w < 8; ++w) {
            unsigned long long ok = red[it & 1][w];
            if (ok > gkey) gkey = ok;
        }
        int win = (int)(~(unsigned)gkey);
        float4 c = xyz_s[win];
        lx = c.x; ly = c.y; lz = c.z;
        if (tid == 0) {
            size_t bp = (size_t)b * Pnp + it;
            new_xyz[bp * 3 + 0] = c.x;
            new_xyz[bp * 3 + 1] = c.y;
            new_xyz[bp * 3 + 2] = c.z;
        }
    }
}

// ---------------------------------------------------------------- ball query
__global__ __launch_bounds__(256) void ballq_kernel(const float* __restrict__ xyz, const float* __restrict__ new_xyz,
                                                    int* __restrict__ gidx) {
    __shared__ float xyz_s[Kpt * 3];
    __shared__ int idxbuf[64][16];
    __shared__ int have_s[64];
    int bx = blockIdx.x;
    int b = bx >> 4, chunk = bx & 15;
    int tid = threadIdx.x, w = tid >> 6, lane = tid & 63;
    for (int e = tid; e < Kpt * 3; e += 256) xyz_s[e] = xyz[(size_t)b * Kpt * 3 + e];
    __syncthreads();
    const float R2 = (float)(0.3 * 0.3);
    unsigned long long lmask = (lane == 63) ? 0x7fffffffffffffffull : ((1ull << lane) - 1ull);
    for (int t = 0; t < 16; ++t) {
        int ql = w * 16 + t;
        size_t bp = (size_t)b * Pnp + chunk * 64 + ql;
        float nx = new_xyz[bp * 3 + 0], ny = new_xyz[bp * 3 + 1], nz = new_xyz[bp * 3 + 2];
        int have = 0;
        for (int r = 0; r < 64; ++r) {
            int k = r * 64 + lane;
            float dx = __fsub_rn(nx, xyz_s[k * 3 + 0]);
            float dy = __fsub_rn(ny, xyz_s[k * 3 + 1]);
            float dz = __fsub_rn(nz, xyz_s[k * 3 + 2]);
            float d2 = __fadd_rn(__fadd_rn(__fmul_rn(dx, dx), __fmul_rn(dy, dy)), __fmul_rn(dz, dz));
            bool inb = d2 < R2;
            unsigned long long mask = __ballot(inb);
            if (mask) {
                int rank = __popcll(mask & lmask);
                if (inb && (have + rank) < 16) idxbuf[ql][have + rank] = k;
                have += __popcll(mask);
                if (have >= 16) break;
            }
        }
        if (lane == 0) have_s[ql] = (have > 16) ? 16 : have;
    }
    __syncthreads();
    for (int e = tid; e < 1024; e += 256) {
        int ql = e >> 4, slot = e & 15;
        int h = have_s[ql];
        int v = (h == 0) ? (Kpt - 1) : ((slot < h) ? idxbuf[ql][slot] : idxbuf[ql][0]);
        size_t bp = (size_t)b * Pnp + chunk * 64 + ql;
        gidx[bp * 16 + slot] = v;
    }
}

// ---------------------------------------------------------------- GEMM layer0: gathered input, y = h @ w0^T
__global__ __launch_bounds__(256) void gemm_gather(const float* __restrict__ ft, const float* __restrict__ w0t,
                                                   const float* __restrict__ xyz, const float* __restrict__ new_xyz,
                                                   const int* __restrict__ gidx, const float* __restrict__ w0,
                                                   float* __restrict__ yout) {
    __shared__ float As[32][68];
    __shared__ float Bs[32][132];
    __shared__ float gxyz_s[64][4];
    __shared__ float w03s[128][4];
    __shared__ int k_s[64];
    int tid = threadIdx.x;
    size_t rblk = (size_t)blockIdx.x * 64;
    int b = (int)(rblk >> 14); // /16384
    if (tid < 64) {
        size_t r = rblk + tid;
        int kg = gidx[r];
        k_s[tid] = kg;
        size_t bp = r >> 4;
#pragma unroll
        for (int c = 0; c < 3; ++c) {
            float gx = (xyz[((size_t)b * Kpt + kg) * 3 + c] - new_xyz[bp * 3 + c]) / 0.3f;
            gxyz_s[tid][c] = gx;
        }
    } else if (tid < 192) {
        int o = tid - 64;
#pragma unroll
        for (int c = 0; c < 3; ++c) w03s[o][c] = w0[(size_t)o * 259 + c];
    }
    __syncthreads();
    int i = tid >> 2, cq = tid & 3;
    const float* Arow = ft + ((size_t)b * Kpt + k_s[i]) * Cft;
    int kkB = tid >> 3, oq = tid & 7;
    int ty = tid >> 4, tx = tid & 15;
    float acc[4][8];
#pragma unroll
    for (int ii = 0; ii < 4; ++ii)
#pragma unroll
        for (int jj = 0; jj < 8; ++jj) acc[ii][jj] = 0.f;

    for (int kt = 0; kt < 8; ++kt) {
        int c0 = kt * 32;
        float4 a0 = *(const float4*)(Arow + c0 + cq * 4);
        float4 a1 = *(const float4*)(Arow + c0 + cq * 4 + 16);
        float4 bv[4];
#pragma unroll
        for (int q = 0; q < 4; ++q)
            bv[q] = *(const float4*)(w0t + (size_t)(c0 + kkB) * 128 + oq * 16 + q * 4);
        __syncthreads();
        As[cq * 4 + 0][i] = a0.x; As[cq * 4 + 1][i] = a0.y; As[cq * 4 + 2][i] = a0.z; As[cq * 4 + 3][i] = a0.w;
        As[cq * 4 + 16][i] = a1.x; As[cq * 4 + 17][i] = a1.y; As[cq * 4 + 18][i] = a1.z; As[cq * 4 + 19][i] = a1.w;
#pragma unroll
        for (int q = 0; q < 4; ++q)
            *(float4*)&Bs[kkB][oq * 16 + q * 4] = bv[q];
        __syncthreads();
#pragma unroll
        for (int kk = 0; kk < 32; ++kk) {
            float4 av = *(const float4*)&As[kk][ty * 4];
            float4 b0 = *(const float4*)&Bs[kk][tx * 8];
            float4 b1 = *(const float4*)&Bs[kk][tx * 8 + 4];
            float a_[4] = {av.x, av.y, av.z, av.w};
            float b_[8] = {b0.x, b0.y, b0.z, b0.w, b1.x, b1.y, b1.z, b1.w};
#pragma unroll
            for (int ii = 0; ii < 4; ++ii)
#pragma unroll
                for (int jj = 0; jj < 8; ++jj) acc[ii][jj] += a_[ii] * b_[jj];
        }
    }
    // epilogue: xyz rank-3 contribution + store
#pragma unroll
    for (int ii = 0; ii < 4; ++ii) {
        int rowl = ty * 4 + ii;
        float g0 = gxyz_s[rowl][0], g1 = gxyz_s[rowl][1], g2 = gxyz_s[rowl][2];
        float out[8];
#pragma unroll
        for (int jj = 0; jj < 8; ++jj) {
            int o = tx * 8 + jj;
            out[jj] = acc[ii][jj] + g0 * w03s[o][0] + g1 * w03s[o][1] + g2 * w03s[o][2];
        }
        size_t row = rblk + rowl;
        *(float4*)(yout + row * 128 + tx * 8) = make_float4(out[0], out[1], out[2], out[3]);
        *(float4*)(yout + row * 128 + tx * 8 + 4) = make_float4(out[4], out[5], out[6], out[7]);
    }
}

// ---------------------------------------------------------------- generic GEMM with optional fused input-BN-ReLU; may run in place
__global__ __launch_bounds__(256) void gemm_bn(const float* Ain, const float* __restrict__ wt, float* Aout,
                                               const float* __restrict__ stats, const float* __restrict__ gamma,
                                               const float* __restrict__ beta, const float* __restrict__ bias,
                                               int Kc, float invN) {
    __shared__ float As[32][68];
    __shared__ float Bs[32][132];
    __shared__ float scs[128], shs[128];
    int tid = threadIdx.x;
    bool hasT = (stats != nullptr);
    if (hasT && tid < 128) {
        float m = stats[tid] * invN;
        float v = stats[128 + tid] * invN - m * m;
        float sc = gamma[tid] / sqrtf(v + 1e-5f);
        scs[tid] = sc;
        shs[tid] = beta[tid] - m * sc;
    }
    size_t rblk = (size_t)blockIdx.x * 64;
    int i = tid >> 2, cq = tid & 3;
    const float* Arow = Ain + (rblk + i) * Kc;
    int kkB = tid >> 3, oq = tid & 7;
    int ty = tid >> 4, tx = tid & 15;
    float acc[4][8];
#pragma unroll
    for (int ii = 0; ii < 4; ++ii)
#pragma unroll
        for (int jj = 0; jj < 8; ++jj) acc[ii][jj] = 0.f;

    int nk = Kc >> 5;
    for (int kt = 0; kt < nk; ++kt) {
        int c0 = kt * 32;
        float4 a0 = *(const float4*)(Arow + c0 + cq * 4);
        float4 a1 = *(const float4*)(Arow + c0 + cq * 4 + 16);
        float4 bv[4];
#pragma unroll
        for (int q = 0; q < 4; ++q)
            bv[q] = *(const float4*)(wt + (size_t)(c0 + kkB) * 128 + oq * 16 + q * 4);
        __syncthreads();
        if (hasT) {
            int cb = c0 + cq * 4;
            a0.x = fmaxf(0.f, a0.x * scs[cb + 0] + shs[cb + 0]);
            a0.y = fmaxf(0.f, a0.y * scs[cb + 1] + shs[cb + 1]);
            a0.z = fmaxf(0.f, a0.z * scs[cb + 2] + shs[cb + 2]);
            a0.w = fmaxf(0.f, a0.w * scs[cb + 3] + shs[cb + 3]);
            a1.x = fmaxf(0.f, a1.x * scs[cb + 16] + shs[cb + 16]);
            a1.y = fmaxf(0.f, a1.y * scs[cb + 17] + shs[cb + 17]);
            a1.z = fmaxf(0.f, a1.z * scs[cb + 18] + shs[cb + 18]);
            a1.w = fmaxf(0.f, a1.w * scs[cb + 19] + shs[cb + 19]);
        }
        As[cq * 4 + 0][i] = a0.x; As[cq * 4 + 1][i] = a0.y; As[cq * 4 + 2][i] = a0.z; As[cq * 4 + 3][i] = a0.w;
        As[cq * 4 + 16][i] = a1.x; As[cq * 4 + 17][i] = a1.y; As[cq * 4 + 18][i] = a1.z; As[cq * 4 + 19][i] = a1.w;
#pragma unroll
        for (int q = 0; q < 4; ++q)
            *(float4*)&Bs[kkB][oq * 16 + q * 4] = bv[q];
        __syncthreads();
#pragma unroll
        for (int kk = 0; kk < 32; ++kk) {
            float4 av = *(const float4*)&As[kk][ty * 4];
            float4 b0 = *(const float4*)&Bs[kk][tx * 8];
            float4 b1 = *(const float4*)&Bs[kk][tx * 8 + 4];
            float a_[4] = {av.x, av.y, av.z, av.w};
            float b_[8] = {b0.x, b0.y, b0.z, b0.w, b1.x, b1.y, b1.z, b1.w};
#pragma unroll
            for (int ii = 0; ii < 4; ++ii)
#pragma unroll
                for (int jj = 0; jj < 8; ++jj) acc[ii][jj] += a_[ii] * b_[jj];
        }
    }
#pragma unroll
    for (int ii = 0; ii < 4; ++ii) {
        size_t row = rblk + ty * 4 + ii;
        float out[8];
#pragma unroll
        for (int jj = 0; jj < 8; ++jj) {
            int o = tx * 8 + jj;
            out[jj] = acc[ii][jj] + (bias ? bias[o] : 0.f);
        }
        *(float4*)(Aout + row * 128 + tx * 8) = make_float4(out[0], out[1], out[2], out[3]);
        *(float4*)(Aout + row * 128 + tx * 8 + 4) = make_float4(out[4], out[5], out[6], out[7]);
    }
}

// ---------------------------------------------------------------- per-channel sum/sumsq (stats pre-zeroed)
__global__ __launch_bounds__(256) void stats_k(const float* __restrict__ y, float* __restrict__ st) {
    __shared__ float ssum[256], ssq[256];
    int tid = threadIdx.x;
    int o = tid & 127, h = tid >> 7;
    size_t r0 = (size_t)blockIdx.x * 256;
    float sum = 0.f, sq = 0.f;
#pragma unroll 4
    for (int i = 0; i < 128; ++i) {
        float v = y[(r0 + i * 2 + h) * 128 + o];
        sum += v;
        sq += v * v;
    }
    ssum[tid] = sum; ssq[tid] = sq;
    __syncthreads();
    if (tid < 128) {
        atomicAdd(&st[o], ssum[tid] + ssum[tid + 128]);
        atomicAdd(&st[128 + o], ssq[tid] + ssq[tid + 128]);
    }
}

// ---------------------------------------------------------------- BN+ReLU+max over s
__global__ __launch_bounds__(256) void maxpool_k(const float* __restrict__ y, const float* __restrict__ st,
                                                 const float* __restrict__ gamma, const float* __restrict__ beta,
                                                 float* __restrict__ agg) {
    int tid = threadIdx.x;
    int o = tid & 127, h = tid >> 7;
    size_t bp = (size_t)blockIdx.x * 2 + h;
    const float invN = 1.f / (float)M0;
    float m = st[o] * invN;
    float v = st[128 + o] * invN - m * m;
    float sc = gamma[o] / sqrtf(v + 1e-5f);
    float sh = beta[o] - m * sc;
    float best = 0.f;
#pragma unroll
    for (int s = 0; s < 16; ++s) {
        float vv = y[(bp * 16 + s) * 128 + o];
        best = fmaxf(best, fmaxf(0.f, vv * sc + sh));
    }
    agg[bp * 128 + o] = best;
}

// ---------------------------------------------------------------- final: n2=BN-ReLU(yf), net=n2@w3^T+b3, out assembly
__global__ __launch_bounds__(256) void final_k(const float* __restrict__ yf, const float* __restrict__ st,
                                               const float* __restrict__ gamma, const float* __restrict__ beta,
                                               const float* __restrict__ w3, const float* __restrict__ b3,
                                               const float* __restrict__ new_xyz, float* __restrict__ out) {
    __shared__ float n2s[8][128];
    __shared__ float w3s[22 * 132];
    __shared__ float scf[128], shf[128];
    int tid = threadIdx.x;
    size_t r0 = (size_t)blockIdx.x * 8;
    if (tid < 128) {
        const float invN = 1.f / (float)M1;
        float m = st[tid] * invN;
        float v = st[128 + tid] * invN - m * m;
        float sc = gamma[tid] / sqrtf(v + 1e-5f);
        scf[tid] = sc;
        shf[tid] = beta[tid] - m * sc;
    }
    __syncthreads();
#pragma unroll
    for (int i = 0; i < 4; ++i) {
        int e = tid + i * 256;
        int rl = e >> 7, c = e & 127;
        float raw = yf[(r0 + rl) * 128 + c];
        n2s[rl][c] = fmaxf(0.f, raw * scf[c] + shf[c]);
    }
#pragma unroll
    for (int i = 0; i < 11; ++i) {
        int e = tid + i * 256;
        int o = e >> 7, c = e & 127;
        w3s[o * 132 + c] = w3[e];
    }
    __syncthreads();
    int rl = tid >> 5, o = tid & 31;
    if (o < OUTCH) {
        float dot = 0.f;
#pragma unroll 4
        for (int c = 0; c < 128; ++c) dot += n2s[rl][c] * w3s[o * 132 + c];
        float v = dot + b3[o];
        if (o < 3) v += new_xyz[(r0 + rl) * 3 + o];
        out[(r0 + rl) * OUTCH + o] = v;
    }
}

extern "C" void kernel_launch(void* const* d_in, const int* in_sizes, int n_in,
                              void* d_out, int out_size, void* d_ws, size_t ws_size,
                              hipStream_t stream) {
    (void)in_sizes; (void)n_in; (void)out_size; (void)ws_size;
    const float* xyz = (const float*)d_in[0];
    const float* features = (const float*)d_in[1];
    const float* w0 = (const float*)d_in[2];
    const float* g0 = (const float*)d_in[3];
    const float* be0 = (const float*)d_in[4];
    const float* w1m = (const float*)d_in[5];
    const float* g1m = (const float*)d_in[6];
    const float* be1m = (const float*)d_in[7];
    const float* w2m = (const float*)d_in[8];
    const float* g2m = (const float*)d_in[9];
    const float* be2m = (const float*)d_in[10];
    const float* wf1 = (const float*)d_in[11];
    const float* bf1 = (const float*)d_in[12];
    const float* gf1 = (const float*)d_in[13];
    const float* bef1 = (const float*)d_in[14];
    const float* wf2 = (const float*)d_in[15];
    const float* bf2 = (const float*)d_in[16];
    const float* gf2 = (const float*)d_in[17];
    const float* bef2 = (const float*)d_in[18];
    const float* w3 = (const float*)d_in[19];
    const float* b3 = (const float*)d_in[20];
    float* ws = (float*)d_ws;
    float* ft = ws + OFF_FT;
    float* yA = ws + OFF_YA;
    float* agg = ws + OFF_AGG;
    float* yF = ws + OFF_YF;
    float* st = ws + OFF_STATS;
    int* gidx = (int*)(ws + OFF_GIDX);
    float* nxyz = ws + OFF_NEWXYZ;

    hipMemsetAsync((void*)st, 0, 5 * 256 * sizeof(float), stream);

    transpose_feat<<<dim3(Kpt / 32, Cft / 32, Bsz), dim3(32, 8), 0, stream>>>(features, ft);
    transpose_w<<<128, 256, 0, stream>>>(w0, ws + OFF_W0T, 128, 256, 259, 3);
    transpose_w<<<64, 256, 0, stream>>>(w1m, ws + OFF_W1T, 128, 128, 128, 0);
    transpose_w<<<64, 256, 0, stream>>>(w2m, ws + OFF_W2T, 128, 128, 128, 0);
    transpose_w<<<64, 256, 0, stream>>>(wf1, ws + OFF_WF1T, 128, 128, 128, 0);
    transpose_w<<<64, 256, 0, stream>>>(wf2, ws + OFF_WF2T, 128, 128, 128, 0);

    fps_kernel<<<Bsz, 512, 0, stream>>>(xyz, nxyz);
    ballq_kernel<<<256, 256, 0, stream>>>(xyz, nxyz, gidx);

    gemm_gather<<<M0 / 64, 256, 0, stream>>>(ft, ws + OFF_W0T, xyz, nxyz, gidx, w0, yA);
    stats_k<<<M0 / 256, 256, 0, stream>>>(yA, st);
    gemm_bn<<<M0 / 64, 256, 0, stream>>>(yA, ws + OFF_W1T, yA, st, g0, be0, nullptr, 128, 1.f / (float)M0);
    stats_k<<<M0 / 256, 256, 0, stream>>>(yA, st + 256);
    gemm_bn<<<M0 / 64, 256, 0, stream>>>(yA, ws + OFF_W2T, yA, st + 256, g1m, be1m, nullptr, 128, 1.f / (float)M0);
    stats_k<<<M0 / 256, 256, 0, stream>>>(yA, st + 512);
    maxpool_k<<<M1 / 2, 256, 0, stream>>>(yA, st + 512, g2m, be2m, agg);

    gemm_bn<<<M1 / 64, 256, 0, stream>>>(agg, ws + OFF_WF1T, yF, nullptr, nullptr, nullptr, bf1, 128, 0.f);
    stats_k<<<M1 / 256, 256, 0, stream>>>(yF, st + 768);
    gemm_bn<<<M1 / 64, 256, 0, stream>>>(yF, ws + OFF_WF2T, yF, st + 768, gf1, bef1, bf2, 128, 1.f / (float)M1);
    stats_k<<<M1 / 256, 256, 0, stream>>>(yF, st + 1024);
    final_k<<<M1 / 8, 256, 0, stream>>>(yF, st + 1024, gf2, bef2, w3, b3, nxyz, (float*)d_out);
}

// Round 3
// 1602.083 us; speedup vs baseline: 1.5701x; 1.1446x over previous
//
#include <hip/hip_runtime.h>
#include <math.h>

// Problem constants
#define Bsz 16
#define Kpt 4096
#define Cft 256
#define Pnp 1024
#define Smp 16
#define Hch 128
#define OUTCH 22
#define M0 (Bsz * Pnp * Smp)   // 262144
#define M1 (Bsz * Pnp)         // 16384

// Workspace layout (in floats)
#define OFF_FT      ((size_t)0)                    // 16777216  ft: (B,K,C)
#define OFF_YA      ((size_t)16777216)             // 33554432  activations (M0 x 128)
#define OFF_AGG     ((size_t)50331648)             // 2097152   agg (M1 x 128)
#define OFF_YF      ((size_t)52428800)             // 2097152   FC activations (M1 x 128)
#define OFF_W0T     ((size_t)54525952)             // 32768     w0 feat part transposed (256x128)
#define OFF_W1T     ((size_t)54558720)             // 16384
#define OFF_W2T     ((size_t)54575104)             // 16384
#define OFF_WF1T    ((size_t)54591488)             // 16384
#define OFF_WF2T    ((size_t)54607872)             // 16384
#define OFF_STATS   ((size_t)54624256)             // 5*256
#define OFF_GIDX    ((size_t)54625536)             // 262144 (int)
#define OFF_NEWXYZ  ((size_t)54887680)             // 49152

// ---------------------------------------------------------------- transpose features (B,C,K)->(B,K,C)
__global__ __launch_bounds__(256) void transpose_feat(const float* __restrict__ f, float* __restrict__ ft) {
    __shared__ float tile[32][33];
    int b = blockIdx.z;
    int k0 = blockIdx.x * 32, c0 = blockIdx.y * 32;
    int tx = threadIdx.x, ty = threadIdx.y; // 32 x 8
#pragma unroll
    for (int j = 0; j < 4; ++j) {
        int c = c0 + ty + j * 8;
        tile[ty + j * 8][tx] = f[((size_t)b * Cft + c) * Kpt + k0 + tx];
    }
    __syncthreads();
#pragma unroll
    for (int j = 0; j < 4; ++j) {
        int k = k0 + ty + j * 8;
        ft[((size_t)b * Kpt + k) * Cft + c0 + tx] = tile[tx][ty + j * 8];
    }
}

// ---------------------------------------------------------------- small weight transpose dst[c*O+o]=src[o*stride+off+c]
__global__ __launch_bounds__(256) void transpose_w(const float* __restrict__ src, float* __restrict__ dst,
                                                   int O, int Cs, int stride, int off) {
    int idx = blockIdx.x * 256 + threadIdx.x;
    if (idx < O * Cs) {
        int o = idx % O, c = idx / O;
        dst[idx] = src[(size_t)o * stride + off + c];
    }
}

// ---------------------------------------------------------------- FPS v3: 256 thr, 16 pts/lane in regs,
// DPP intra-wave u64-key max (VALU latency, no LDS), 1 barrier/iter.
template <int CTRL>
__device__ __forceinline__ unsigned long long dpp_max_step(unsigned long long key) {
    int lo = (int)(unsigned)key, hi = (int)(key >> 32);
    int slo = __builtin_amdgcn_update_dpp(0, lo, CTRL, 0xf, 0xf, true);
    int shi = __builtin_amdgcn_update_dpp(0, hi, CTRL, 0xf, 0xf, true);
    unsigned long long other = ((unsigned long long)(unsigned)shi << 32) | (unsigned)slo;
    return other > key ? other : key;  // keys >= 0; bound_ctrl zero-fill is neutral for max
}

__global__ __launch_bounds__(256) void fps_kernel(const float* __restrict__ xyz, float* __restrict__ new_xyz) {
    __shared__ float4 xyz_s[Kpt];                 // stride-4 pad: winner coords in one ds_read_b128
    __shared__ unsigned long long red[2][4];      // parity-double-buffered per-wave winners
    int b = blockIdx.x, tid = threadIdx.x;
    int wid = tid >> 6, lane = tid & 63;

    for (int k = tid; k < Kpt; k += 256) {
        float x = xyz[(size_t)b * Kpt * 3 + k * 3 + 0];
        float y = xyz[(size_t)b * Kpt * 3 + k * 3 + 1];
        float z = xyz[(size_t)b * Kpt * 3 + k * 3 + 2];
        xyz_s[k] = make_float4(x, y, z, 0.f);
    }
    __syncthreads();

    float px[16], py[16], pz[16], mind[16];
#pragma unroll
    for (int j = 0; j < 16; ++j) {
        float4 p = xyz_s[tid + j * 256];
        px[j] = p.x; py[j] = p.y; pz[j] = p.z;
        mind[j] = 1e10f;
    }
    float lx = xyz_s[0].x, ly = xyz_s[0].y, lz = xyz_s[0].z;
    if (tid == 0) {
        new_xyz[(size_t)b * Pnp * 3 + 0] = lx;
        new_xyz[(size_t)b * Pnp * 3 + 1] = ly;
        new_xyz[(size_t)b * Pnp * 3 + 2] = lz;
    }

    for (int it = 1; it < Pnp; ++it) {
        // local update + argmax (exact reference arithmetic: no fma contraction)
        float bestv = -1.0f;
        int bestk = 0;
#pragma unroll
        for (int j = 0; j < 16; ++j) {
            float dx = __fsub_rn(px[j], lx);
            float dy = __fsub_rn(py[j], ly);
            float dz = __fsub_rn(pz[j], lz);
            float d = __fadd_rn(__fadd_rn(__fmul_rn(dx, dx), __fmul_rn(dy, dy)), __fmul_rn(dz, dz));
            float m = fminf(mind[j], d);
            mind[j] = m;
            if (m > bestv) { bestv = m; bestk = tid + j * 256; }  // j asc == k asc: strict > keeps lowest k
        }
        // pack: d>=0 so float bit-order == value order; ~k gives lowest-index tie-break under max
        unsigned long long key = ((unsigned long long)__float_as_uint(bestv) << 32) | (unsigned)(~bestk);
        // 64-lane max via DPP: row_shr 1/2/4/8 then row_bcast15/31 -> lane63 holds wave max
        key = dpp_max_step<0x111>(key);
        key = dpp_max_step<0x112>(key);
        key = dpp_max_step<0x114>(key);
        key = dpp_max_step<0x118>(key);
        key = dpp_max_step<0x142>(key);
        key = dpp_max_step<0x143>(key);
        if (lane == 63) red[it & 1][wid] = key;
        __syncthreads();
        unsigned long long gkey = red[it & 1][0];
#pragma unroll
        for (int w = 1; w < 4; ++w) {
            unsigned long long ok = red[it & 1][w];
            if (ok > gkey) gkey = ok;
        }
        int win = (int)(~(unsigned)gkey);
        float4 c = xyz_s[win];
        lx = c.x; ly = c.y; lz = c.z;
        if (tid == 0) {
            size_t bp = (size_t)b * Pnp + it;
            new_xyz[bp * 3 + 0] = c.x;
            new_xyz[bp * 3 + 1] = c.y;
            new_xyz[bp * 3 + 2] = c.z;
        }
    }
}

// ---------------------------------------------------------------- ball query
__global__ __launch_bounds__(256) void ballq_kernel(const float* __restrict__ xyz, const float* __restrict__ new_xyz,
                                                    int* __restrict__ gidx) {
    __shared__ float xyz_s[Kpt * 3];
    __shared__ int idxbuf[64][16];
    __shared__ int have_s[64];
    int bx = blockIdx.x;
    int b = bx >> 4, chunk = bx & 15;
    int tid = threadIdx.x, w = tid >> 6, lane = tid & 63;
    for (int e = tid; e < Kpt * 3; e += 256) xyz_s[e] = xyz[(size_t)b * Kpt * 3 + e];
    __syncthreads();
    const float R2 = (float)(0.3 * 0.3);
    unsigned long long lmask = (lane == 63) ? 0x7fffffffffffffffull : ((1ull << lane) - 1ull);
    for (int t = 0; t < 16; ++t) {
        int ql = w * 16 + t;
        size_t bp = (size_t)b * Pnp + chunk * 64 + ql;
        float nx = new_xyz[bp * 3 + 0], ny = new_xyz[bp * 3 + 1], nz = new_xyz[bp * 3 + 2];
        int have = 0;
        for (int r = 0; r < 64; ++r) {
            int k = r * 64 + lane;
            float dx = __fsub_rn(nx, xyz_s[k * 3 + 0]);
            float dy = __fsub_rn(ny, xyz_s[k * 3 + 1]);
            float dz = __fsub_rn(nz, xyz_s[k * 3 + 2]);
            float d2 = __fadd_rn(__fadd_rn(__fmul_rn(dx, dx), __fmul_rn(dy, dy)), __fmul_rn(dz, dz));
            bool inb = d2 < R2;
            unsigned long long mask = __ballot(inb);
            if (mask) {
                int rank = __popcll(mask & lmask);
                if (inb && (have + rank) < 16) idxbuf[ql][have + rank] = k;
                have += __popcll(mask);
                if (have >= 16) break;
            }
        }
        if (lane == 0) have_s[ql] = (have > 16) ? 16 : have;
    }
    __syncthreads();
    for (int e = tid; e < 1024; e += 256) {
        int ql = e >> 4, slot = e & 15;
        int h = have_s[ql];
        int v = (h == 0) ? (Kpt - 1) : ((slot < h) ? idxbuf[ql][slot] : idxbuf[ql][0]);
        size_t bp = (size_t)b * Pnp + chunk * 64 + ql;
        gidx[bp * 16 + slot] = v;
    }
}

// ---------------------------------------------------------------- GEMM layer0: gathered input, y = h @ w0^T
__global__ __launch_bounds__(256) void gemm_gather(const float* __restrict__ ft, const float* __restrict__ w0t,
                                                   const float* __restrict__ xyz, const float* __restrict__ new_xyz,
                                                   const int* __restrict__ gidx, const float* __restrict__ w0,
                                                   float* __restrict__ yout) {
    __shared__ float As[32][68];
    __shared__ float Bs[32][132];
    __shared__ float gxyz_s[64][4];
    __shared__ float w03s[128][4];
    __shared__ int k_s[64];
    int tid = threadIdx.x;
    size_t rblk = (size_t)blockIdx.x * 64;
    int b = (int)(rblk >> 14); // /16384
    if (tid < 64) {
        size_t r = rblk + tid;
        int kg = gidx[r];
        k_s[tid] = kg;
        size_t bp = r >> 4;
#pragma unroll
        for (int c = 0; c < 3; ++c) {
            float gx = (xyz[((size_t)b * Kpt + kg) * 3 + c] - new_xyz[bp * 3 + c]) / 0.3f;
            gxyz_s[tid][c] = gx;
        }
    } else if (tid < 192) {
        int o = tid - 64;
#pragma unroll
        for (int c = 0; c < 3; ++c) w03s[o][c] = w0[(size_t)o * 259 + c];
    }
    __syncthreads();
    int i = tid >> 2, cq = tid & 3;
    const float* Arow = ft + ((size_t)b * Kpt + k_s[i]) * Cft;
    int kkB = tid >> 3, oq = tid & 7;
    int ty = tid >> 4, tx = tid & 15;
    float acc[4][8];
#pragma unroll
    for (int ii = 0; ii < 4; ++ii)
#pragma unroll
        for (int jj = 0; jj < 8; ++jj) acc[ii][jj] = 0.f;

    for (int kt = 0; kt < 8; ++kt) {
        int c0 = kt * 32;
        float4 a0 = *(const float4*)(Arow + c0 + cq * 4);
        float4 a1 = *(const float4*)(Arow + c0 + cq * 4 + 16);
        float4 bv[4];
#pragma unroll
        for (int q = 0; q < 4; ++q)
            bv[q] = *(const float4*)(w0t + (size_t)(c0 + kkB) * 128 + oq * 16 + q * 4);
        __syncthreads();
        As[cq * 4 + 0][i] = a0.x; As[cq * 4 + 1][i] = a0.y; As[cq * 4 + 2][i] = a0.z; As[cq * 4 + 3][i] = a0.w;
        As[cq * 4 + 16][i] = a1.x; As[cq * 4 + 17][i] = a1.y; As[cq * 4 + 18][i] = a1.z; As[cq * 4 + 19][i] = a1.w;
#pragma unroll
        for (int q = 0; q < 4; ++q)
            *(float4*)&Bs[kkB][oq * 16 + q * 4] = bv[q];
        __syncthreads();
#pragma unroll
        for (int kk = 0; kk < 32; ++kk) {
            float4 av = *(const float4*)&As[kk][ty * 4];
            float4 b0 = *(const float4*)&Bs[kk][tx * 8];
            float4 b1 = *(const float4*)&Bs[kk][tx * 8 + 4];
            float a_[4] = {av.x, av.y, av.z, av.w};
            float b_[8] = {b0.x, b0.y, b0.z, b0.w, b1.x, b1.y, b1.z, b1.w};
#pragma unroll
            for (int ii = 0; ii < 4; ++ii)
#pragma unroll
                for (int jj = 0; jj < 8; ++jj) acc[ii][jj] += a_[ii] * b_[jj];
        }
    }
    // epilogue: xyz rank-3 contribution + store
#pragma unroll
    for (int ii = 0; ii < 4; ++ii) {
        int rowl = ty * 4 + ii;
        float g0 = gxyz_s[rowl][0], g1 = gxyz_s[rowl][1], g2 = gxyz_s[rowl][2];
        float out[8];
#pragma unroll
        for (int jj = 0; jj < 8; ++jj) {
            int o = tx * 8 + jj;
            out[jj] = acc[ii][jj] + g0 * w03s[o][0] + g1 * w03s[o][1] + g2 * w03s[o][2];
        }
        size_t row = rblk + rowl;
        *(float4*)(yout + row * 128 + tx * 8) = make_float4(out[0], out[1], out[2], out[3]);
        *(float4*)(yout + row * 128 + tx * 8 + 4) = make_float4(out[4], out[5], out[6], out[7]);
    }
}

// ---------------------------------------------------------------- generic GEMM with optional fused input-BN-ReLU; may run in place
__global__ __launch_bounds__(256) void gemm_bn(const float* Ain, const float* __restrict__ wt, float* Aout,
                                               const float* __restrict__ stats, const float* __restrict__ gamma,
                                               const float* __restrict__ beta, const float* __restrict__ bias,
                                               int Kc, float invN) {
    __shared__ float As[32][68];
    __shared__ float Bs[32][132];
    __shared__ float scs[128], shs[128];
    int tid = threadIdx.x;
    bool hasT = (stats != nullptr);
    if (hasT && tid < 128) {
        float m = stats[tid] * invN;
        float v = stats[128 + tid] * invN - m * m;
        float sc = gamma[tid] / sqrtf(v + 1e-5f);
        scs[tid] = sc;
        shs[tid] = beta[tid] - m * sc;
    }
    size_t rblk = (size_t)blockIdx.x * 64;
    int i = tid >> 2, cq = tid & 3;
    const float* Arow = Ain + (rblk + i) * Kc;
    int kkB = tid >> 3, oq = tid & 7;
    int ty = tid >> 4, tx = tid & 15;
    float acc[4][8];
#pragma unroll
    for (int ii = 0; ii < 4; ++ii)
#pragma unroll
        for (int jj = 0; jj < 8; ++jj) acc[ii][jj] = 0.f;

    int nk = Kc >> 5;
    for (int kt = 0; kt < nk; ++kt) {
        int c0 = kt * 32;
        float4 a0 = *(const float4*)(Arow + c0 + cq * 4);
        float4 a1 = *(const float4*)(Arow + c0 + cq * 4 + 16);
        float4 bv[4];
#pragma unroll
        for (int q = 0; q < 4; ++q)
            bv[q] = *(const float4*)(wt + (size_t)(c0 + kkB) * 128 + oq * 16 + q * 4);
        __syncthreads();
        if (hasT) {
            int cb = c0 + cq * 4;
            a0.x = fmaxf(0.f, a0.x * scs[cb + 0] + shs[cb + 0]);
            a0.y = fmaxf(0.f, a0.y * scs[cb + 1] + shs[cb + 1]);
            a0.z = fmaxf(0.f, a0.z * scs[cb + 2] + shs[cb + 2]);
            a0.w = fmaxf(0.f, a0.w * scs[cb + 3] + shs[cb + 3]);
            a1.x = fmaxf(0.f, a1.x * scs[cb + 16] + shs[cb + 16]);
            a1.y = fmaxf(0.f, a1.y * scs[cb + 17] + shs[cb + 17]);
            a1.z = fmaxf(0.f, a1.z * scs[cb + 18] + shs[cb + 18]);
            a1.w = fmaxf(0.f, a1.w * scs[cb + 19] + shs[cb + 19]);
        }
        As[cq * 4 + 0][i] = a0.x; As[cq * 4 + 1][i] = a0.y; As[cq * 4 + 2][i] = a0.z; As[cq * 4 + 3][i] = a0.w;
        As[cq * 4 + 16][i] = a1.x; As[cq * 4 + 17][i] = a1.y; As[cq * 4 + 18][i] = a1.z; As[cq * 4 + 19][i] = a1.w;
#pragma unroll
        for (int q = 0; q < 4; ++q)
            *(float4*)&Bs[kkB][oq * 16 + q * 4] = bv[q];
        __syncthreads();
#pragma unroll
        for (int kk = 0; kk < 32; ++kk) {
            float4 av = *(const float4*)&As[kk][ty * 4];
            float4 b0 = *(const float4*)&Bs[kk][tx * 8];
            float4 b1 = *(const float4*)&Bs[kk][tx * 8 + 4];
            float a_[4] = {av.x, av.y, av.z, av.w};
            float b_[8] = {b0.x, b0.y, b0.z, b0.w, b1.x, b1.y, b1.z, b1.w};
#pragma unroll
            for (int ii = 0; ii < 4; ++ii)
#pragma unroll
                for (int jj = 0; jj < 8; ++jj) acc[ii][jj] += a_[ii] * b_[jj];
        }
    }
#pragma unroll
    for (int ii = 0; ii < 4; ++ii) {
        size_t row = rblk + ty * 4 + ii;
        float out[8];
#pragma unroll
        for (int jj = 0; jj < 8; ++jj) {
            int o = tx * 8 + jj;
            out[jj] = acc[ii][jj] + (bias ? bias[o] : 0.f);
        }
        *(float4*)(Aout + row * 128 + tx * 8) = make_float4(out[0], out[1], out[2], out[3]);
        *(float4*)(Aout + row * 128 + tx * 8 + 4) = make_float4(out[4], out[5], out[6], out[7]);
    }
}

// ---------------------------------------------------------------- per-channel sum/sumsq (stats pre-zeroed)
__global__ __launch_bounds__(256) void stats_k(const float* __restrict__ y, float* __restrict__ st) {
    __shared__ float ssum[256], ssq[256];
    int tid = threadIdx.x;
    int o = tid & 127, h = tid >> 7;
    size_t r0 = (size_t)blockIdx.x * 256;
    float sum = 0.f, sq = 0.f;
#pragma unroll 4
    for (int i = 0; i < 128; ++i) {
        float v = y[(r0 + i * 2 + h) * 128 + o];
        sum += v;
        sq += v * v;
    }
    ssum[tid] = sum; ssq[tid] = sq;
    __syncthreads();
    if (tid < 128) {
        atomicAdd(&st[o], ssum[tid] + ssum[tid + 128]);
        atomicAdd(&st[128 + o], ssq[tid] + ssq[tid + 128]);
    }
}

// ---------------------------------------------------------------- BN+ReLU+max over s
__global__ __launch_bounds__(256) void maxpool_k(const float* __restrict__ y, const float* __restrict__ st,
                                                 const float* __restrict__ gamma, const float* __restrict__ beta,
                                                 float* __restrict__ agg) {
    int tid = threadIdx.x;
    int o = tid & 127, h = tid >> 7;
    size_t bp = (size_t)blockIdx.x * 2 + h;
    const float invN = 1.f / (float)M0;
    float m = st[o] * invN;
    float v = st[128 + o] * invN - m * m;
    float sc = gamma[o] / sqrtf(v + 1e-5f);
    float sh = beta[o] - m * sc;
    float best = 0.f;
#pragma unroll
    for (int s = 0; s < 16; ++s) {
        float vv = y[(bp * 16 + s) * 128 + o];
        best = fmaxf(best, fmaxf(0.f, vv * sc + sh));
    }
    agg[bp * 128 + o] = best;
}

// ---------------------------------------------------------------- final: n2=BN-ReLU(yf), net=n2@w3^T+b3, out assembly
__global__ __launch_bounds__(256) void final_k(const float* __restrict__ yf, const float* __restrict__ st,
                                               const float* __restrict__ gamma, const float* __restrict__ beta,
                                               const float* __restrict__ w3, const float* __restrict__ b3,
                                               const float* __restrict__ new_xyz, float* __restrict__ out) {
    __shared__ float n2s[8][128];
    __shared__ float w3s[22 * 132];
    __shared__ float scf[128], shf[128];
    int tid = threadIdx.x;
    size_t r0 = (size_t)blockIdx.x * 8;
    if (tid < 128) {
        const float invN = 1.f / (float)M1;
        float m = st[tid] * invN;
        float v = st[128 + tid] * invN - m * m;
        float sc = gamma[tid] / sqrtf(v + 1e-5f);
        scf[tid] = sc;
        shf[tid] = beta[tid] - m * sc;
    }
    __syncthreads();
#pragma unroll
    for (int i = 0; i < 4; ++i) {
        int e = tid + i * 256;
        int rl = e >> 7, c = e & 127;
        float raw = yf[(r0 + rl) * 128 + c];
        n2s[rl][c] = fmaxf(0.f, raw * scf[c] + shf[c]);
    }
#pragma unroll
    for (int i = 0; i < 11; ++i) {
        int e = tid + i * 256;
        int o = e >> 7, c = e & 127;
        w3s[o * 132 + c] = w3[e];
    }
    __syncthreads();
    int rl = tid >> 5, o = tid & 31;
    if (o < OUTCH) {
        float dot = 0.f;
#pragma unroll 4
        for (int c = 0; c < 128; ++c) dot += n2s[rl][c] * w3s[o * 132 + c];
        float v = dot + b3[o];
        if (o < 3) v += new_xyz[(r0 + rl) * 3 + o];
        out[(r0 + rl) * OUTCH + o] = v;
    }
}

extern "C" void kernel_launch(void* const* d_in, const int* in_sizes, int n_in,
                              void* d_out, int out_size, void* d_ws, size_t ws_size,
                              hipStream_t stream) {
    (void)in_sizes; (void)n_in; (void)out_size; (void)ws_size;
    const float* xyz = (const float*)d_in[0];
    const float* features = (const float*)d_in[1];
    const float* w0 = (const float*)d_in[2];
    const float* g0 = (const float*)d_in[3];
    const float* be0 = (const float*)d_in[4];
    const float* w1m = (const float*)d_in[5];
    const float* g1m = (const float*)d_in[6];
    const float* be1m = (const float*)d_in[7];
    const float* w2m = (const float*)d_in[8];
    const float* g2m = (const float*)d_in[9];
    const float* be2m = (const float*)d_in[10];
    const float* wf1 = (const float*)d_in[11];
    const float* bf1 = (const float*)d_in[12];
    const float* gf1 = (const float*)d_in[13];
    const float* bef1 = (const float*)d_in[14];
    const float* wf2 = (const float*)d_in[15];
    const float* bf2 = (const float*)d_in[16];
    const float* gf2 = (const float*)d_in[17];
    const float* bef2 = (const float*)d_in[18];
    const float* w3 = (const float*)d_in[19];
    const float* b3 = (const float*)d_in[20];
    float* ws = (float*)d_ws;
    float* ft = ws + OFF_FT;
    float* yA = ws + OFF_YA;
    float* agg = ws + OFF_AGG;
    float* yF = ws + OFF_YF;
    float* st = ws + OFF_STATS;
    int* gidx = (int*)(ws + OFF_GIDX);
    float* nxyz = ws + OFF_NEWXYZ;

    hipMemsetAsync((void*)st, 0, 5 * 256 * sizeof(float), stream);

    transpose_feat<<<dim3(Kpt / 32, Cft / 32, Bsz), dim3(32, 8), 0, stream>>>(features, ft);
    transpose_w<<<128, 256, 0, stream>>>(w0, ws + OFF_W0T, 128, 256, 259, 3);
    transpose_w<<<64, 256, 0, stream>>>(w1m, ws + OFF_W1T, 128, 128, 128, 0);
    transpose_w<<<64, 256, 0, stream>>>(w2m, ws + OFF_W2T, 128, 128, 128, 0);
    transpose_w<<<64, 256, 0, stream>>>(wf1, ws + OFF_WF1T, 128, 128, 128, 0);
    transpose_w<<<64, 256, 0, stream>>>(wf2, ws + OFF_WF2T, 128, 128, 128, 0);

    fps_kernel<<<Bsz, 256, 0, stream>>>(xyz, nxyz);
    ballq_kernel<<<256, 256, 0, stream>>>(xyz, nxyz, gidx);

    gemm_gather<<<M0 / 64, 256, 0, stream>>>(ft, ws + OFF_W0T, xyz, nxyz, gidx, w0, yA);
    stats_k<<<M0 / 256, 256, 0, stream>>>(yA, st);
    gemm_bn<<<M0 / 64, 256, 0, stream>>>(yA, ws + OFF_W1T, yA, st, g0, be0, nullptr, 128, 1.f / (float)M0);
    stats_k<<<M0 / 256, 256, 0, stream>>>(yA, st + 256);
    gemm_bn<<<M0 / 64, 256, 0, stream>>>(yA, ws + OFF_W2T, yA, st + 256, g1m, be1m, nullptr, 128, 1.f / (float)M0);
    stats_k<<<M0 / 256, 256, 0, stream>>>(yA, st + 512);
    maxpool_k<<<M1 / 2, 256, 0, stream>>>(yA, st + 512, g2m, be2m, agg);

    gemm_bn<<<M1 / 64, 256, 0, stream>>>(agg, ws + OFF_WF1T, yF, nullptr, nullptr, nullptr, bf1, 128, 0.f);
    stats_k<<<M1 / 256, 256, 0, stream>>>(yF, st + 768);
    gemm_bn<<<M1 / 64, 256, 0, stream>>>(yF, ws + OFF_WF2T, yF, st + 768, gf1, bef1, bf2, 128, 1.f / (float)M1);
    stats_k<<<M1 / 256, 256, 0, stream>>>(yF, st + 1024);
    final_k<<<M1 / 8, 256, 0, stream>>>(yF, st + 1024, gf2, bef2, w3, b3, nxyz, (float*)d_out);
}